// Round 1
// baseline (1122.176 us; speedup 1.0000x reference)
//
#include <hip/hip_runtime.h>
#include <cstddef>

// Problem constants (fixed by setup_inputs)
static constexpr int Wd  = 256;   // sequence length (width)
static constexpr int NBd = 128;   // batch = hn*bs
static constexpr int Cd  = 128;   // channels
static constexpr int NHd = 8;     // attention heads
static constexpr int HDd = 16;    // head dim
static constexpr int BSd = 2;     // bs
static constexpr int HNd = 64;    // hn
static constexpr int Pd  = 511;   // 2*W-1 distinct relative positions
static constexpr size_t SEQF = (size_t)Wd * NBd * Cd;  // 4,194,304 floats

// ---------------- to_seq: feat (bs,c,hn,w) -> seq (w, n=h*bs+b, c) ----------------
__global__ __launch_bounds__(256) void k_to_seq(const float* __restrict__ feat,
                                                float* __restrict__ out) {
  __shared__ float tile[32][33];
  int wi0 = blockIdx.x * 32, ci0 = blockIdx.y * 32;
  int hb = blockIdx.z;
  int h = hb >> 1, b = hb & 1;
  int tx = threadIdx.x, ty = threadIdx.y;
#pragma unroll
  for (int r = 0; r < 4; ++r) {
    int ci = ci0 + ty + r * 8;
    tile[ty + r * 8][tx] = feat[(((size_t)b * Cd + ci) * HNd + h) * Wd + wi0 + tx];
  }
  __syncthreads();
  int n = h * BSd + b;
#pragma unroll
  for (int r = 0; r < 4; ++r) {
    int wi = wi0 + ty + r * 8;
    out[((size_t)wi * NBd + n) * Cd + ci0 + tx] = tile[tx][ty + r * 8];
  }
}

// ---------------- from_seq: seq (w,n,c) -> feat (bs,c,hn,w) ----------------
__global__ __launch_bounds__(256) void k_from_seq(const float* __restrict__ seq,
                                                  float* __restrict__ feat) {
  __shared__ float tile[32][33];
  int wi0 = blockIdx.x * 32, ci0 = blockIdx.y * 32;
  int hb = blockIdx.z;
  int h = hb >> 1, b = hb & 1;
  int n = h * BSd + b;
  int tx = threadIdx.x, ty = threadIdx.y;
#pragma unroll
  for (int r = 0; r < 4; ++r) {
    int wi = wi0 + ty + r * 8;
    tile[ty + r * 8][tx] = seq[((size_t)wi * NBd + n) * Cd + ci0 + tx];
  }
  __syncthreads();
#pragma unroll
  for (int r = 0; r < 4; ++r) {
    int ci = ci0 + ty + r * 8;
    feat[(((size_t)b * Cd + ci) * HNd + h) * Wd + wi0 + tx] = tile[tx][ty + r * 8];
  }
}

// ---------------- LayerNorm over c (row per block, 128 threads) ----------------
__global__ __launch_bounds__(128) void k_ln(const float* __restrict__ in,
                                            float* __restrict__ out,
                                            const float* __restrict__ g,
                                            const float* __restrict__ bb) {
  __shared__ float red[4];
  int row = blockIdx.x, t = threadIdx.x;
  float x = in[(size_t)row * Cd + t];
  float s1 = x, s2 = x * x;
#pragma unroll
  for (int m = 1; m < 64; m <<= 1) {
    s1 += __shfl_xor(s1, m);
    s2 += __shfl_xor(s2, m);
  }
  int wid = t >> 6;
  if ((t & 63) == 0) { red[wid * 2] = s1; red[wid * 2 + 1] = s2; }
  __syncthreads();
  float S1 = red[0] + red[2], S2 = red[1] + red[3];
  float mean = S1 * (1.0f / Cd);
  float var  = S2 * (1.0f / Cd) - mean * mean;
  float r = rsqrtf(var + 1e-5f);
  out[(size_t)row * Cd + t] = (x - mean) * r * g[t] + bb[t];
}

// ---------------- GEMM: out[m,n] = sN(m? no, per-n)*(A[m,:]·Wt[n,:] + bias[n]) (+res)
// A: M x 128 row-major. Wt: rows are output cols (n), 128 wide. K = 128 fixed.
// Columns n < scaleN0 get *scale (applied to dot+bias). res (optional) added after.
__global__ __launch_bounds__(256) void k_gemm(const float* __restrict__ A,
                                              const float* __restrict__ Wt,
                                              const float* __restrict__ bias,
                                              const float* __restrict__ res,
                                              float* __restrict__ out,
                                              int M, int ldout,
                                              int scaleN0, float scale) {
  __shared__ __align__(16) float As[64][68];
  __shared__ __align__(16) float Bs[64][68];
  int m0 = blockIdx.x * 64;
  int n0 = blockIdx.y * 64;
  int tid = threadIdx.x;
  int tx = tid & 15, ty = tid >> 4;
  float acc[4][4] = {{0.f}};
  for (int kt = 0; kt < 2; ++kt) {
    __syncthreads();
#pragma unroll
    for (int r = 0; r < 4; ++r) {
      int idx = tid + r * 256;
      int row = idx >> 4, c4 = idx & 15;
      int m = m0 + row;
      float4 av = make_float4(0.f, 0.f, 0.f, 0.f);
      if (m < M) av = *(const float4*)&A[(size_t)m * Cd + kt * 64 + c4 * 4];
      *(float4*)&As[row][c4 * 4] = av;
      *(float4*)&Bs[row][c4 * 4] =
          *(const float4*)&Wt[(size_t)(n0 + row) * Cd + kt * 64 + c4 * 4];
    }
    __syncthreads();
#pragma unroll
    for (int k4 = 0; k4 < 16; ++k4) {
      float4 a[4], b[4];
#pragma unroll
      for (int i = 0; i < 4; ++i) a[i] = *(float4*)&As[ty + 16 * i][k4 * 4];
#pragma unroll
      for (int j = 0; j < 4; ++j) b[j] = *(float4*)&Bs[tx + 16 * j][k4 * 4];
#pragma unroll
      for (int i = 0; i < 4; ++i)
#pragma unroll
        for (int j = 0; j < 4; ++j)
          acc[i][j] += a[i].x * b[j].x + a[i].y * b[j].y + a[i].z * b[j].z + a[i].w * b[j].w;
    }
  }
#pragma unroll
  for (int i = 0; i < 4; ++i) {
    int m = m0 + ty + 16 * i;
    if (m >= M) continue;
#pragma unroll
    for (int j = 0; j < 4; ++j) {
      int n = n0 + tx + 16 * j;
      float v = acc[i][j] + bias[n];
      if (n < scaleN0) v *= scale;
      if (res) v += res[(size_t)m * ldout + n];
      out[(size_t)m * ldout + n] = v;
    }
  }
}

// ---------------- Fused attention ----------------
// grid (8 i-tiles, 128 n), block 512. Per block: loop e in [0,8), j in 2 phases of 128
// (online softmax). attn[n,e,i,j] = q·k + q·PK[p] + k·PQ[p];
// pass==2: p=i-j+255 ; pass==1: p=j-i+255 (flipped pos).
// PP: (511,256) rows = [PQ(scaled) | PK].
// raw (pass2): sum over e of pre-softmax attn -> (bs,hn,w,w).
__global__ __launch_bounds__(512) void k_attn(const float* __restrict__ Qp, int ldq,
                                              const float* __restrict__ Kp,
                                              const float* __restrict__ Vp, int ldkv,
                                              const float* __restrict__ PP,
                                              float* __restrict__ O,
                                              float* __restrict__ raw, int pass) {
  __shared__ __align__(16) float Kh[128][20];
  __shared__ __align__(16) float Vh[128][20];
  __shared__ __align__(16) float PQb[160][20];
  __shared__ __align__(16) float PKb[160][20];
  int t = threadIdx.x;
  int ii = t >> 4, jg = t & 15;
  int i0 = blockIdx.x * 32;
  int n = blockIdx.y;
  int i = i0 + ii;
  float rawacc[16];
#pragma unroll
  for (int z = 0; z < 16; ++z) rawacc[z] = 0.f;

  for (int e = 0; e < NHd; ++e) {
    float po[16];
#pragma unroll
    for (int d = 0; d < 16; ++d) po[d] = 0.f;
    float mrow = -1e30f, den = 0.f;
    float q[16];
    {
      const float4* qr = (const float4*)&Qp[((size_t)i * NBd + n) * ldq + e * HDd];
#pragma unroll
      for (int d4 = 0; d4 < 4; ++d4) {
        float4 v4 = qr[d4];
        q[d4 * 4 + 0] = v4.x; q[d4 * 4 + 1] = v4.y;
        q[d4 * 4 + 2] = v4.z; q[d4 * 4 + 3] = v4.w;
      }
    }
    for (int jt = 0; jt < 2; ++jt) {
      int j0 = jt << 7;
      int pstart = (pass == 2) ? (i0 - j0 + 128) : (j0 - i0 + 224);
      __syncthreads();
      {  // stage K/V: 128 rows x 4 float4 = 512 units (exactly one per thread)
        int j = t >> 2, d4 = t & 3;
        *(float4*)&Kh[j][d4 * 4] =
            *(const float4*)&Kp[((size_t)(j0 + j) * NBd + n) * ldkv + e * HDd + d4 * 4];
        *(float4*)&Vh[j][d4 * 4] =
            *(const float4*)&Vp[((size_t)(j0 + j) * NBd + n) * ldkv + e * HDd + d4 * 4];
      }
      for (int u = t; u < 636; u += 512) {  // stage pos bands: 159 rows x 4 float4
        int r = u >> 2, d4 = u & 3;
        int p = pstart + r;
        *(float4*)&PQb[r][d4 * 4] = *(const float4*)&PP[(size_t)p * 256 + e * HDd + d4 * 4];
        *(float4*)&PKb[r][d4 * 4] = *(const float4*)&PP[(size_t)p * 256 + 128 + e * HDd + d4 * 4];
      }
      __syncthreads();
      float S[8];
      float mloc = -1e30f;
#pragma unroll
      for (int jj = 0; jj < 8; ++jj) {
        int jl = jg + (jj << 4);
        int r = (pass == 2) ? (ii - jl + 127) : (jl - ii + 31);
        const float4* kr = (const float4*)Kh[jl];
        const float4* pk = (const float4*)PKb[r];
        const float4* pq = (const float4*)PQb[r];
        float s = 0.f;
#pragma unroll
        for (int d4 = 0; d4 < 4; ++d4) {
          float4 kv = kr[d4], k2 = pk[d4], q2 = pq[d4];
          s += q[d4 * 4 + 0] * (kv.x + k2.x) + kv.x * q2.x;
          s += q[d4 * 4 + 1] * (kv.y + k2.y) + kv.y * q2.y;
          s += q[d4 * 4 + 2] * (kv.z + k2.z) + kv.z * q2.z;
          s += q[d4 * 4 + 3] * (kv.w + k2.w) + kv.w * q2.w;
        }
        S[jj] = s;
        mloc = fmaxf(mloc, s);
        rawacc[jt * 8 + jj] += s;
      }
#pragma unroll
      for (int m = 1; m < 16; m <<= 1) mloc = fmaxf(mloc, __shfl_xor(mloc, m));
      float mnew = fmaxf(mrow, mloc);
      float alpha = __expf(mrow - mnew);
      den *= alpha;
#pragma unroll
      for (int d = 0; d < 16; ++d) po[d] *= alpha;
      mrow = mnew;
#pragma unroll
      for (int jj = 0; jj < 8; ++jj) {
        float pl = __expf(S[jj] - mrow);
        den += pl;
        int jl = jg + (jj << 4);
        const float4* vr = (const float4*)Vh[jl];
#pragma unroll
        for (int d4 = 0; d4 < 4; ++d4) {
          float4 v4 = vr[d4];
          po[d4 * 4 + 0] += pl * v4.x; po[d4 * 4 + 1] += pl * v4.y;
          po[d4 * 4 + 2] += pl * v4.z; po[d4 * 4 + 3] += pl * v4.w;
        }
      }
    }  // jt
#pragma unroll
    for (int m = 1; m < 16; m <<= 1) den += __shfl_xor(den, m);
#pragma unroll
    for (int d = 0; d < 16; ++d) {
#pragma unroll
      for (int m = 1; m < 16; m <<= 1) po[d] += __shfl_xor(po[d], m);
    }
    float inv = 1.0f / den;
    O[((size_t)i * NBd + n) * Cd + e * HDd + jg] = po[jg] * inv;
  }  // e
  if (raw) {
    int b = n & 1, h = n >> 1;
    float* rr = &raw[(((size_t)b * HNd + h) * Wd + i) * Wd];
#pragma unroll
    for (int z = 0; z < 16; ++z) {
      int j = ((z >> 3) << 7) + jg + ((z & 7) << 4);
      rr[j] = rawacc[z];
    }
  }
}

extern "C" void kernel_launch(void* const* d_in, const int* in_sizes, int n_in,
                              void* d_out, int out_size, void* d_ws, size_t ws_size,
                              hipStream_t stream) {
  const float* feat_l = (const float*)d_in[0];
  const float* feat_r = (const float*)d_in[1];
  const float* pos    = (const float*)d_in[2];
  // d_in[3] = pos_indexes (int) -- structure is known analytically, unused.
  const float* Wqkv = (const float*)d_in[4];
  const float* bqkv = (const float*)d_in[5];
  const float* Wo   = (const float*)d_in[6];
  const float* bo   = (const float*)d_in[7];
  const float* g1   = (const float*)d_in[8];
  const float* b1   = (const float*)d_in[9];
  const float* g2   = (const float*)d_in[10];
  const float* b2   = (const float*)d_in[11];
  float* out = (float*)d_out;

  float* ws = (float*)d_ws;
  float* fl_seq = ws;                       // holds fl; later frb2 goes to fr_seq slot
  float* fr_seq = ws + SEQF;
  float* fl2    = ws + 2 * SEQF;            // later: attention output O
  float* fr2    = ws + 3 * SEQF;            // later: fr_new
  float* Qr     = ws + 4 * SEQF;            // later: fl_new
  float* QKVl   = ws + 5 * SEQF;            // 3*SEQF (32768 x 384)
  float* KVr2   = ws + 8 * SEQF;            // 2*SEQF (32768 x 256)
  float* PPb    = ws + 10 * SEQF;           // 511 x 256

  dim3 tgrid(8, 4, 128), tblk(32, 8);
  k_to_seq<<<tgrid, tblk, 0, stream>>>(feat_l, fl_seq);
  k_to_seq<<<tgrid, tblk, 0, stream>>>(feat_r, fr_seq);
  k_ln<<<32768, 128, 0, stream>>>(fl_seq, fl2, g1, b1);
  k_ln<<<32768, 128, 0, stream>>>(fr_seq, fr2, g1, b1);

  // PP = [PQ(scaled)|PK] projections of the 511 pos rows
  k_gemm<<<dim3(8, 4), 256, 0, stream>>>(pos, Wqkv, bqkv, nullptr, PPb, Pd, 256, 128, 0.25f);
  // QKV of fl2 (Q scaled)
  k_gemm<<<dim3(512, 6), 256, 0, stream>>>(fl2, Wqkv, bqkv, nullptr, QKVl, 32768, 384, 128, 0.25f);
  // Q of fr2 (scaled)
  k_gemm<<<dim3(512, 2), 256, 0, stream>>>(fr2, Wqkv, bqkv, nullptr, Qr, 32768, 128, 128, 0.25f);

  // mha1: q=fr2-proj, kv=fl2-proj, flipped pos => p = j-i+255
  k_attn<<<dim3(8, 128), 512, 0, stream>>>(Qr, Cd, QKVl + 128, QKVl + 256, 384, PPb,
                                           /*O=*/fl2, nullptr, 1);
  // fr_new = fr_seq + O @ Wo^T + bo
  k_gemm<<<dim3(512, 2), 256, 0, stream>>>(fl2, Wo, bo, fr_seq, fr2, 32768, 128, 0, 1.0f);
  // frb2 = ln(fr_new, g2, b2) -> fr_seq slot
  k_ln<<<32768, 128, 0, stream>>>(fr2, fl_seq == nullptr ? nullptr : fr_seq, g2, b2);
  // KV of frb2
  k_gemm<<<dim3(512, 4), 256, 0, stream>>>(fr_seq, Wqkv + 128 * Cd, bqkv + 128, nullptr,
                                           KVr2, 32768, 256, 0, 1.0f);
  // mha2: q=fl2-proj (in QKVl), kv=frb2-proj; p = i-j+255; writes raw
  k_attn<<<dim3(8, 128), 512, 0, stream>>>(QKVl, 384, KVr2, KVr2 + 128, 256, PPb,
                                           /*O=*/fl2, out + 2 * SEQF, 2);
  // fl_new = fl_seq + O @ Wo^T + bo  -> Qr slot
  k_gemm<<<dim3(512, 2), 256, 0, stream>>>(fl2, Wo, bo, fl_seq, Qr, 32768, 128, 0, 1.0f);

  k_from_seq<<<tgrid, tblk, 0, stream>>>(Qr, out);
  k_from_seq<<<tgrid, tblk, 0, stream>>>(fr2, out + SEQF);

  (void)in_sizes; (void)n_in; (void)out_size; (void)ws_size;
}

// Round 2
// 784.266 us; speedup vs baseline: 1.4309x; 1.4309x over previous
//
#include <hip/hip_runtime.h>
#include <cstddef>

// Problem constants (fixed by setup_inputs)
static constexpr int Wd  = 256;   // sequence length (width)
static constexpr int NBd = 128;   // batch = hn*bs
static constexpr int Cd  = 128;   // channels
static constexpr int BSd = 2;     // bs
static constexpr int HNd = 64;    // hn
static constexpr int Pd  = 511;   // 2*W-1 distinct relative positions
static constexpr size_t SEQF = (size_t)Wd * NBd * Cd;  // 4,194,304 floats

typedef __attribute__((ext_vector_type(8))) short bf16x8;
typedef __attribute__((ext_vector_type(4))) short bf16x4;
typedef __attribute__((ext_vector_type(4))) float f32x4;

__device__ inline short f2bf(float f) {
  union { float f; unsigned u; } v; v.f = f;
  return (short)((v.u + 0x7FFFu + ((v.u >> 16) & 1u)) >> 16);
}

// ---------------- to_seq: feat (bs,c,hn,w) -> seq (w, n=h*bs+b, c) ----------------
__global__ __launch_bounds__(256) void k_to_seq(const float* __restrict__ feat,
                                                float* __restrict__ out) {
  __shared__ float tile[32][33];
  int wi0 = blockIdx.x * 32, ci0 = blockIdx.y * 32;
  int hb = blockIdx.z;
  int h = hb >> 1, b = hb & 1;
  int tx = threadIdx.x, ty = threadIdx.y;
#pragma unroll
  for (int r = 0; r < 4; ++r) {
    int ci = ci0 + ty + r * 8;
    tile[ty + r * 8][tx] = feat[(((size_t)b * Cd + ci) * HNd + h) * Wd + wi0 + tx];
  }
  __syncthreads();
  int n = h * BSd + b;
#pragma unroll
  for (int r = 0; r < 4; ++r) {
    int wi = wi0 + ty + r * 8;
    out[((size_t)wi * NBd + n) * Cd + ci0 + tx] = tile[tx][ty + r * 8];
  }
}

// ---------------- from_seq: seq (w,n,c) -> feat (bs,c,hn,w) ----------------
__global__ __launch_bounds__(256) void k_from_seq(const float* __restrict__ seq,
                                                  float* __restrict__ feat) {
  __shared__ float tile[32][33];
  int wi0 = blockIdx.x * 32, ci0 = blockIdx.y * 32;
  int hb = blockIdx.z;
  int h = hb >> 1, b = hb & 1;
  int n = h * BSd + b;
  int tx = threadIdx.x, ty = threadIdx.y;
#pragma unroll
  for (int r = 0; r < 4; ++r) {
    int wi = wi0 + ty + r * 8;
    tile[ty + r * 8][tx] = seq[((size_t)wi * NBd + n) * Cd + ci0 + tx];
  }
  __syncthreads();
#pragma unroll
  for (int r = 0; r < 4; ++r) {
    int ci = ci0 + ty + r * 8;
    feat[(((size_t)b * Cd + ci) * HNd + h) * Wd + wi0 + tx] = tile[tx][ty + r * 8];
  }
}

// ---------------- LayerNorm over c (row per block, 128 threads) ----------------
__global__ __launch_bounds__(128) void k_ln(const float* __restrict__ in,
                                            float* __restrict__ out,
                                            const float* __restrict__ g,
                                            const float* __restrict__ bb) {
  __shared__ float red[4];
  int row = blockIdx.x, t = threadIdx.x;
  float x = in[(size_t)row * Cd + t];
  float s1 = x, s2 = x * x;
#pragma unroll
  for (int m = 1; m < 64; m <<= 1) {
    s1 += __shfl_xor(s1, m);
    s2 += __shfl_xor(s2, m);
  }
  int wid = t >> 6;
  if ((t & 63) == 0) { red[wid * 2] = s1; red[wid * 2 + 1] = s2; }
  __syncthreads();
  float S1 = red[0] + red[2], S2 = red[1] + red[3];
  float mean = S1 * (1.0f / Cd);
  float var  = S2 * (1.0f / Cd) - mean * mean;
  float r = rsqrtf(var + 1e-5f);
  out[(size_t)row * Cd + t] = (x - mean) * r * g[t] + bb[t];
}

// ---------------- fp32 GEMM (unchanged from R1; next round: MFMA) ----------------
__global__ __launch_bounds__(256) void k_gemm(const float* __restrict__ A,
                                              const float* __restrict__ Wt,
                                              const float* __restrict__ bias,
                                              const float* __restrict__ res,
                                              float* __restrict__ out,
                                              int M, int ldout,
                                              int scaleN0, float scale) {
  __shared__ __align__(16) float As[64][68];
  __shared__ __align__(16) float Bs[64][68];
  int m0 = blockIdx.x * 64;
  int n0 = blockIdx.y * 64;
  int tid = threadIdx.x;
  int tx = tid & 15, ty = tid >> 4;
  float acc[4][4] = {{0.f}};
  for (int kt = 0; kt < 2; ++kt) {
    __syncthreads();
#pragma unroll
    for (int r = 0; r < 4; ++r) {
      int idx = tid + r * 256;
      int row = idx >> 4, c4 = idx & 15;
      int m = m0 + row;
      float4 av = make_float4(0.f, 0.f, 0.f, 0.f);
      if (m < M) av = *(const float4*)&A[(size_t)m * Cd + kt * 64 + c4 * 4];
      *(float4*)&As[row][c4 * 4] = av;
      *(float4*)&Bs[row][c4 * 4] =
          *(const float4*)&Wt[(size_t)(n0 + row) * Cd + kt * 64 + c4 * 4];
    }
    __syncthreads();
#pragma unroll
    for (int k4 = 0; k4 < 16; ++k4) {
      float4 a[4], b[4];
#pragma unroll
      for (int i = 0; i < 4; ++i) a[i] = *(float4*)&As[ty + 16 * i][k4 * 4];
#pragma unroll
      for (int j = 0; j < 4; ++j) b[j] = *(float4*)&Bs[tx + 16 * j][k4 * 4];
#pragma unroll
      for (int i = 0; i < 4; ++i)
#pragma unroll
        for (int j = 0; j < 4; ++j)
          acc[i][j] += a[i].x * b[j].x + a[i].y * b[j].y + a[i].z * b[j].z + a[i].w * b[j].w;
    }
  }
#pragma unroll
  for (int i = 0; i < 4; ++i) {
    int m = m0 + ty + 16 * i;
    if (m >= M) continue;
#pragma unroll
    for (int j = 0; j < 4; ++j) {
      int n = n0 + tx + 16 * j;
      float v = acc[i][j] + bias[n];
      if (n < scaleN0) v *= scale;
      if (res) v += res[(size_t)m * ldout + n];
      out[(size_t)m * ldout + n] = v;
    }
  }
}

// ---------------- MFMA fused attention ----------------
// Block = (i-panel of 64 rows, n). 256 threads = 4 waves; wave w owns i-tile
// it0 = i0p + 16w. Loop e (8 heads): stage Q-panel/K/V^T + PQ/PK windows (bf16)
// in LDS, then per 16x16 j-tile:
//   St  = K_tile @ Q_tile^T                  (S^T in C-layout: row=j, col=i)
//   R2t = Q_tile @ PKwin^T  (rows i, cols p) -> LDS, gather R2[i, p(i,j)]
//   R3t = K_tile @ PQwin^T  (rows j, cols p) -> LDS, gather R3[j, p(i,j)]
//   s = St + g2 + g3 ; p = exp(s) (no max-sub: |s| small) ; den += p
//   P^T (B-layout) via per-wave LDS bounce; every 2 tiles: Ot += V^T @ P^T (K=32)
// PASS==2: p = i-j+255 (window base i0p). PASS==1: p = j-i+255 (base 192-i0p).
// RAW (pass 2): rawacc[j] summed over e in regs -> (bs,hn,w,w).
template <int PASS, bool RAW>
__global__ __launch_bounds__(256) void k_attn_mfma(
    const float* __restrict__ Qg, int ldq,
    const float* __restrict__ Kg, const float* __restrict__ Vg, int ldkv,
    const float* __restrict__ PP, float* __restrict__ O,
    float* __restrict__ raw) {
  __shared__ short Ks[256][16];
  __shared__ short Qs[64][16];
  __shared__ short VTs[16][264];
  __shared__ short PQw[320][16];
  __shared__ short PKw[320][16];
  __shared__ float R2s[4][16][34];
  __shared__ float R3s[4][16][34];
  __shared__ short Ps[4][16][40];

  const int t = threadIdx.x;
  const int n = blockIdx.y;
  const int i0p = blockIdx.x * 64;
  const int lane = t & 63, wv = t >> 6;
  const int ml = lane & 15, quad = lane >> 4;
  const bool lo = lane < 32;
  const int wb = (PASS == 2) ? i0p : (192 - i0p);
  const bf16x8 zero8 = {0, 0, 0, 0, 0, 0, 0, 0};
  const f32x4 z4 = {0.f, 0.f, 0.f, 0.f};

  float rawacc[RAW ? 64 : 1];
  if (RAW) {
#pragma unroll
    for (int z = 0; z < (RAW ? 64 : 1); ++z) rawacc[z] = 0.f;
  }

  for (int e = 0; e < 8; ++e) {
    __syncthreads();
    {  // stage Q panel: 64 rows x 16 -> 256 float4 chunks
      int r = t >> 2, c4 = t & 3;
      const float4 v = *(const float4*)&Qg[((size_t)(i0p + r) * NBd + n) * ldq + e * 16 + c4 * 4];
      bf16x4 s; s[0] = f2bf(v.x); s[1] = f2bf(v.y); s[2] = f2bf(v.z); s[3] = f2bf(v.w);
      *(bf16x4*)&Qs[r][c4 * 4] = s;
    }
#pragma unroll
    for (int it = 0; it < 4; ++it) {  // K + V^T: 256 rows x 4 chunks
      int idx = t + it * 256;
      int r = idx >> 2, c4 = idx & 3;
      const float4 kv = *(const float4*)&Kg[((size_t)r * NBd + n) * ldkv + e * 16 + c4 * 4];
      bf16x4 s; s[0] = f2bf(kv.x); s[1] = f2bf(kv.y); s[2] = f2bf(kv.z); s[3] = f2bf(kv.w);
      *(bf16x4*)&Ks[r][c4 * 4] = s;
      const float4 vv = *(const float4*)&Vg[((size_t)r * NBd + n) * ldkv + e * 16 + c4 * 4];
      VTs[c4 * 4 + 0][r] = f2bf(vv.x);
      VTs[c4 * 4 + 1][r] = f2bf(vv.y);
      VTs[c4 * 4 + 2][r] = f2bf(vv.z);
      VTs[c4 * 4 + 3][r] = f2bf(vv.w);
    }
#pragma unroll
    for (int it = 0; it < 5; ++it) {  // PQ/PK windows: 320 rows x 4 chunks
      int idx = t + it * 256;
      int r = idx >> 2, c4 = idx & 3;
      int p = wb + r; if (p > 510) p = 510;
      const float4 pq = *(const float4*)&PP[(size_t)p * 256 + e * 16 + c4 * 4];
      const float4 pk = *(const float4*)&PP[(size_t)p * 256 + 128 + e * 16 + c4 * 4];
      bf16x4 a; a[0] = f2bf(pq.x); a[1] = f2bf(pq.y); a[2] = f2bf(pq.z); a[3] = f2bf(pq.w);
      bf16x4 b; b[0] = f2bf(pk.x); b[1] = f2bf(pk.y); b[2] = f2bf(pk.z); b[3] = f2bf(pk.w);
      *(bf16x4*)&PQw[r][c4 * 4] = a;
      *(bf16x4*)&PKw[r][c4 * 4] = b;
    }
    __syncthreads();

    bf16x8 bQ = lo ? *(const bf16x8*)&Qs[16 * wv + ml][quad * 8] : zero8;
    f32x4 Ot = {0.f, 0.f, 0.f, 0.f};
    float den = 0.f;
#pragma unroll
    for (int jt = 0; jt < 16; ++jt) {
      const int j0 = jt * 16;
      bf16x8 aK = lo ? *(const bf16x8*)&Ks[j0 + ml][quad * 8] : zero8;
      const int pb = (PASS == 2) ? (16 * wv - j0 + 240) : (j0 - 16 * wv + 48);
      bf16x8 bPK0 = lo ? *(const bf16x8*)&PKw[pb + ml][quad * 8] : zero8;
      bf16x8 bPK1 = lo ? *(const bf16x8*)&PKw[pb + 16 + ml][quad * 8] : zero8;
      bf16x8 bPQ0 = lo ? *(const bf16x8*)&PQw[pb + ml][quad * 8] : zero8;
      bf16x8 bPQ1 = lo ? *(const bf16x8*)&PQw[pb + 16 + ml][quad * 8] : zero8;

      f32x4 St  = __builtin_amdgcn_mfma_f32_16x16x32_bf16(aK, bQ, z4, 0, 0, 0);
      f32x4 R2a = __builtin_amdgcn_mfma_f32_16x16x32_bf16(bQ, bPK0, z4, 0, 0, 0);
      f32x4 R2b = __builtin_amdgcn_mfma_f32_16x16x32_bf16(bQ, bPK1, z4, 0, 0, 0);
      f32x4 R3a = __builtin_amdgcn_mfma_f32_16x16x32_bf16(aK, bPQ0, z4, 0, 0, 0);
      f32x4 R3b = __builtin_amdgcn_mfma_f32_16x16x32_bf16(aK, bPQ1, z4, 0, 0, 0);
#pragma unroll
      for (int r = 0; r < 4; ++r) {
        R2s[wv][quad * 4 + r][ml]      = R2a[r];
        R2s[wv][quad * 4 + r][ml + 16] = R2b[r];
        R3s[wv][quad * 4 + r][ml]      = R3a[r];
        R3s[wv][quad * 4 + r][ml + 16] = R3b[r];
      }
#pragma unroll
      for (int r = 0; r < 4; ++r) {
        const int jl = quad * 4 + r;
        const int pcol = (PASS == 2) ? (ml - jl + 15) : (jl - ml + 15);
        float s = St[r] + R2s[wv][ml][pcol] + R3s[wv][jl][pcol];
        if (RAW) rawacc[(RAW ? (jt * 4 + r) : 0)] += s;
        float pe = __expf(s);
        den += pe;
        Ps[wv][ml][(jt & 1) * 16 + jl] = f2bf(pe);
      }
      if (jt & 1) {
        bf16x8 aVT = *(const bf16x8*)&VTs[ml][(jt >> 1) * 32 + quad * 8];
        bf16x8 bP  = *(const bf16x8*)&Ps[wv][ml][quad * 8];
        Ot = __builtin_amdgcn_mfma_f32_16x16x32_bf16(aVT, bP, Ot, 0, 0, 0);
      }
    }
    den += __shfl_xor(den, 16);
    den += __shfl_xor(den, 32);
    float inv = 1.f / den;
    float4 o4;
    o4.x = Ot[0] * inv; o4.y = Ot[1] * inv; o4.z = Ot[2] * inv; o4.w = Ot[3] * inv;
    // Ot element (d = quad*4+r, i = ml): O[(i,n), e*16 + d]
    *(float4*)&O[((size_t)(i0p + 16 * wv + ml) * NBd + n) * Cd + e * 16 + quad * 4] = o4;
  }

  if (RAW) {
    float* rr = &raw[(((size_t)(n & 1) * HNd + (n >> 1)) * Wd + (i0p + 16 * wv + ml)) * Wd];
#pragma unroll
    for (int jt = 0; jt < 16; ++jt) {
      float4 v;
      v.x = rawacc[RAW ? (jt * 4 + 0) : 0];
      v.y = rawacc[RAW ? (jt * 4 + 1) : 0];
      v.z = rawacc[RAW ? (jt * 4 + 2) : 0];
      v.w = rawacc[RAW ? (jt * 4 + 3) : 0];
      *(float4*)&rr[jt * 16 + quad * 4] = v;
    }
  }
}

extern "C" void kernel_launch(void* const* d_in, const int* in_sizes, int n_in,
                              void* d_out, int out_size, void* d_ws, size_t ws_size,
                              hipStream_t stream) {
  const float* feat_l = (const float*)d_in[0];
  const float* feat_r = (const float*)d_in[1];
  const float* pos    = (const float*)d_in[2];
  // d_in[3] = pos_indexes (int) -- structure known analytically, unused.
  const float* Wqkv = (const float*)d_in[4];
  const float* bqkv = (const float*)d_in[5];
  const float* Wo   = (const float*)d_in[6];
  const float* bo   = (const float*)d_in[7];
  const float* g1   = (const float*)d_in[8];
  const float* b1   = (const float*)d_in[9];
  const float* g2   = (const float*)d_in[10];
  const float* b2   = (const float*)d_in[11];
  float* out = (float*)d_out;

  float* ws = (float*)d_ws;
  float* fl_seq = ws;
  float* fr_seq = ws + SEQF;
  float* fl2    = ws + 2 * SEQF;            // later: attention output O
  float* fr2    = ws + 3 * SEQF;            // later: fr_new
  float* Qr     = ws + 4 * SEQF;            // later: fl_new
  float* QKVl   = ws + 5 * SEQF;            // 3*SEQF (32768 x 384)
  float* KVr2   = ws + 8 * SEQF;            // 2*SEQF (32768 x 256)
  float* PPb    = ws + 10 * SEQF;           // 511 x 256

  dim3 tgrid(8, 4, 128), tblk(32, 8);
  k_to_seq<<<tgrid, tblk, 0, stream>>>(feat_l, fl_seq);
  k_to_seq<<<tgrid, tblk, 0, stream>>>(feat_r, fr_seq);
  k_ln<<<32768, 128, 0, stream>>>(fl_seq, fl2, g1, b1);
  k_ln<<<32768, 128, 0, stream>>>(fr_seq, fr2, g1, b1);

  // PP = [PQ(scaled)|PK] projections of the 511 pos rows
  k_gemm<<<dim3(8, 4), 256, 0, stream>>>(pos, Wqkv, bqkv, nullptr, PPb, Pd, 256, 128, 0.25f);
  // QKV of fl2 (Q scaled)
  k_gemm<<<dim3(512, 6), 256, 0, stream>>>(fl2, Wqkv, bqkv, nullptr, QKVl, 32768, 384, 128, 0.25f);
  // Q of fr2 (scaled)
  k_gemm<<<dim3(512, 2), 256, 0, stream>>>(fr2, Wqkv, bqkv, nullptr, Qr, 32768, 128, 128, 0.25f);

  // mha1: q=fr2-proj, kv=fl2-proj, flipped pos => p = j-i+255
  k_attn_mfma<1, false><<<dim3(4, 128), 256, 0, stream>>>(
      Qr, Cd, QKVl + 128, QKVl + 256, 384, PPb, fl2, nullptr);
  // fr_new = fr_seq + O @ Wo^T + bo
  k_gemm<<<dim3(512, 2), 256, 0, stream>>>(fl2, Wo, bo, fr_seq, fr2, 32768, 128, 0, 1.0f);
  // frb2 = ln(fr_new, g2, b2) -> fr_seq slot
  k_ln<<<32768, 128, 0, stream>>>(fr2, fr_seq, g2, b2);
  // KV of frb2
  k_gemm<<<dim3(512, 4), 256, 0, stream>>>(fr_seq, Wqkv + 128 * Cd, bqkv + 128, nullptr,
                                           KVr2, 32768, 256, 0, 1.0f);
  // mha2: q=fl2-proj (in QKVl), kv=frb2-proj; p = i-j+255; writes raw
  k_attn_mfma<2, true><<<dim3(4, 128), 256, 0, stream>>>(
      QKVl, 384, KVr2, KVr2 + 128, 256, PPb, fl2, out + 2 * SEQF);
  // fl_new = fl_seq + O @ Wo^T + bo  -> Qr slot
  k_gemm<<<dim3(512, 2), 256, 0, stream>>>(fl2, Wo, bo, fl_seq, Qr, 32768, 128, 0, 1.0f);

  k_from_seq<<<tgrid, tblk, 0, stream>>>(Qr, out);
  k_from_seq<<<tgrid, tblk, 0, stream>>>(fr2, out + SEQF);

  (void)in_sizes; (void)n_in; (void)out_size; (void)ws_size;
}

// Round 3
// 497.896 us; speedup vs baseline: 2.2538x; 1.5752x over previous
//
#include <hip/hip_runtime.h>
#include <cstddef>

// Problem constants (fixed by setup_inputs)
static constexpr int Wd  = 256;   // sequence length (width)
static constexpr int NBd = 128;   // batch = hn*bs
static constexpr int Cd  = 128;   // channels
static constexpr int BSd = 2;     // bs
static constexpr int HNd = 64;    // hn
static constexpr size_t SEQF = (size_t)Wd * NBd * Cd;  // 4,194,304 elements

typedef __attribute__((ext_vector_type(8))) short bf16x8;
typedef __attribute__((ext_vector_type(4))) short bf16x4;
typedef __attribute__((ext_vector_type(4))) float f32x4;

__device__ inline short f2bf(float f) {
  union { float f; unsigned u; } v; v.f = f;
  return (short)((v.u + 0x7FFFu + ((v.u >> 16) & 1u)) >> 16);
}

// ---------------- to_seq: feat (bs,c,hn,w) -> seq (w, n=h*bs+b, c) fp32 ----------------
__global__ __launch_bounds__(256) void k_to_seq(const float* __restrict__ feat,
                                                float* __restrict__ out) {
  __shared__ float tile[32][33];
  int wi0 = blockIdx.x * 32, ci0 = blockIdx.y * 32;
  int hb = blockIdx.z;
  int h = hb >> 1, b = hb & 1;
  int tx = threadIdx.x, ty = threadIdx.y;
#pragma unroll
  for (int r = 0; r < 4; ++r) {
    int ci = ci0 + ty + r * 8;
    tile[ty + r * 8][tx] = feat[(((size_t)b * Cd + ci) * HNd + h) * Wd + wi0 + tx];
  }
  __syncthreads();
  int n = h * BSd + b;
#pragma unroll
  for (int r = 0; r < 4; ++r) {
    int wi = wi0 + ty + r * 8;
    out[((size_t)wi * NBd + n) * Cd + ci0 + tx] = tile[tx][ty + r * 8];
  }
}

// ---------------- from_seq: seq (w,n,c) fp32 -> feat (bs,c,hn,w) ----------------
__global__ __launch_bounds__(256) void k_from_seq(const float* __restrict__ seq,
                                                  float* __restrict__ feat) {
  __shared__ float tile[32][33];
  int wi0 = blockIdx.x * 32, ci0 = blockIdx.y * 32;
  int hb = blockIdx.z;
  int h = hb >> 1, b = hb & 1;
  int n = h * BSd + b;
  int tx = threadIdx.x, ty = threadIdx.y;
#pragma unroll
  for (int r = 0; r < 4; ++r) {
    int wi = wi0 + ty + r * 8;
    tile[ty + r * 8][tx] = seq[((size_t)wi * NBd + n) * Cd + ci0 + tx];
  }
  __syncthreads();
#pragma unroll
  for (int r = 0; r < 4; ++r) {
    int ci = ci0 + ty + r * 8;
    feat[(((size_t)b * Cd + ci) * HNd + h) * Wd + wi0 + tx] = tile[tx][ty + r * 8];
  }
}

// ---------------- LayerNorm over c: fp32 in -> bf16 out ----------------
__global__ __launch_bounds__(128) void k_ln(const float* __restrict__ in,
                                            short* __restrict__ out,
                                            const float* __restrict__ g,
                                            const float* __restrict__ bb) {
  __shared__ float red[4];
  int row = blockIdx.x, t = threadIdx.x;
  float x = in[(size_t)row * Cd + t];
  float s1 = x, s2 = x * x;
#pragma unroll
  for (int m = 1; m < 64; m <<= 1) {
    s1 += __shfl_xor(s1, m);
    s2 += __shfl_xor(s2, m);
  }
  int wid = t >> 6;
  if ((t & 63) == 0) { red[wid * 2] = s1; red[wid * 2 + 1] = s2; }
  __syncthreads();
  float S1 = red[0] + red[2], S2 = red[1] + red[3];
  float mean = S1 * (1.0f / Cd);
  float var  = S2 * (1.0f / Cd) - mean * mean;
  float r = rsqrtf(var + 1e-5f);
  out[(size_t)row * Cd + t] = f2bf((x - mean) * r * g[t] + bb[t]);
}

// ---------------- one-shot fp32->bf16 weight/pos convert ----------------
__global__ __launch_bounds__(256) void k_cvt(const float* __restrict__ w1, short* d1,  // 49152
                                             const float* __restrict__ w2, short* d2,  // 16384
                                             const float* __restrict__ w3, short* d3)  // 65408
{
  int i = blockIdx.x * 256 + threadIdx.x;
  if (i < 49152) d1[i] = f2bf(w1[i]);
  if (i < 16384) d2[i] = f2bf(w2[i]);
  if (i < 65408) d3[i] = f2bf(w3[i]);
}

// ---------------- bf16 MFMA GEMM, K=128, no LDS, no barriers ----------------
// A (M x 128 bf16 row-major), Wt (N x 128 bf16): out[m,n] = A[m]·Wt[n] + bias[n]
// (cols n<scaleN0 scaled), optional fp32 residual, optional fp32 / bf16 outputs.
// Block 256 thr = 4 waves; block tile 64m x 128n; wave tile 64m x 32n.
__global__ __launch_bounds__(256) void k_gemm_bf(
    const short* __restrict__ A, const short* __restrict__ Wt,
    const float* __restrict__ bias, const float* __restrict__ res,
    float* __restrict__ outF, short* __restrict__ outB,
    int M, int ldout, int scaleN0, float scale) {
  const int t = threadIdx.x;
  const int lane = t & 63, wv = t >> 6;
  const int ml = lane & 15, quad = lane >> 4;
  const int m0 = blockIdx.x * 64;
  const int n0 = blockIdx.y * 128 + wv * 32;
  const bf16x8 zero8 = {0, 0, 0, 0, 0, 0, 0, 0};

  bf16x8 Bfr[2][4];
#pragma unroll
  for (int nf = 0; nf < 2; ++nf)
#pragma unroll
    for (int ks = 0; ks < 4; ++ks)
      Bfr[nf][ks] = *(const bf16x8*)&Wt[(size_t)(n0 + nf * 16 + ml) * 128 + ks * 32 + quad * 8];

  f32x4 acc[4][2];
#pragma unroll
  for (int mf = 0; mf < 4; ++mf)
#pragma unroll
    for (int nf = 0; nf < 2; ++nf) acc[mf][nf] = {0.f, 0.f, 0.f, 0.f};

#pragma unroll
  for (int ks = 0; ks < 4; ++ks) {
    bf16x8 Af[4];
#pragma unroll
    for (int mf = 0; mf < 4; ++mf) {
      int m = m0 + mf * 16 + ml;
      Af[mf] = (m < M) ? *(const bf16x8*)&A[(size_t)m * 128 + ks * 32 + quad * 8] : zero8;
    }
#pragma unroll
    for (int mf = 0; mf < 4; ++mf)
#pragma unroll
      for (int nf = 0; nf < 2; ++nf)
        acc[mf][nf] = __builtin_amdgcn_mfma_f32_16x16x32_bf16(Af[mf], Bfr[nf][ks], acc[mf][nf], 0, 0, 0);
  }

#pragma unroll
  for (int nf = 0; nf < 2; ++nf) {
    int n = n0 + nf * 16 + ml;
    float bi = bias[n];
    float sc = (n < scaleN0) ? scale : 1.0f;
#pragma unroll
    for (int mf = 0; mf < 4; ++mf) {
#pragma unroll
      for (int r = 0; r < 4; ++r) {
        int m = m0 + mf * 16 + quad * 4 + r;
        if (m >= M) continue;
        float v = (acc[mf][nf][r] + bi) * sc;
        if (res) v += res[(size_t)m * ldout + n];
        if (outF) outF[(size_t)m * ldout + n] = v;
        if (outB) outB[(size_t)m * ldout + n] = f2bf(v);
      }
    }
  }
}

// ---------------- MFMA fused attention (bf16 in / bf16 out) ----------------
// Same structure as R2; inputs Q/K/V/PP are bf16, O written bf16.
// PASS==2: p = i-j+255. PASS==1: p = j-i+255. RAW (pass2): raw fp32 (bs,hn,w,w).
template <int PASS, bool RAW>
__global__ __launch_bounds__(256) void k_attn_mfma(
    const short* __restrict__ Qg, int ldq,
    const short* __restrict__ Kg, const short* __restrict__ Vg, int ldkv,
    const short* __restrict__ PP, short* __restrict__ O,
    float* __restrict__ raw) {
  __shared__ short Ks[256][16];
  __shared__ short Qs[64][16];
  __shared__ short VTs[16][264];
  __shared__ short PQw[320][16];
  __shared__ short PKw[320][16];
  __shared__ float R2s[4][16][34];
  __shared__ float R3s[4][16][34];
  __shared__ short Ps[4][16][40];

  const int t = threadIdx.x;
  const int n = blockIdx.y;
  const int i0p = blockIdx.x * 64;
  const int lane = t & 63, wv = t >> 6;
  const int ml = lane & 15, quad = lane >> 4;
  const bool lo = lane < 32;
  const int wb = (PASS == 2) ? i0p : (192 - i0p);
  const bf16x8 zero8 = {0, 0, 0, 0, 0, 0, 0, 0};
  const f32x4 z4 = {0.f, 0.f, 0.f, 0.f};

  float rawacc[RAW ? 64 : 1];
  if (RAW) {
#pragma unroll
    for (int z = 0; z < (RAW ? 64 : 1); ++z) rawacc[z] = 0.f;
  }

  for (int e = 0; e < 8; ++e) {
    __syncthreads();
    {  // stage Q panel: 64 rows x 4 bf16x4 chunks
      int r = t >> 2, c4 = t & 3;
      *(bf16x4*)&Qs[r][c4 * 4] =
          *(const bf16x4*)&Qg[((size_t)(i0p + r) * NBd + n) * ldq + e * 16 + c4 * 4];
    }
#pragma unroll
    for (int it = 0; it < 4; ++it) {  // K + V^T: 256 rows x 4 chunks
      int idx = t + it * 256;
      int r = idx >> 2, c4 = idx & 3;
      *(bf16x4*)&Ks[r][c4 * 4] =
          *(const bf16x4*)&Kg[((size_t)r * NBd + n) * ldkv + e * 16 + c4 * 4];
      bf16x4 vv = *(const bf16x4*)&Vg[((size_t)r * NBd + n) * ldkv + e * 16 + c4 * 4];
      VTs[c4 * 4 + 0][r] = vv[0];
      VTs[c4 * 4 + 1][r] = vv[1];
      VTs[c4 * 4 + 2][r] = vv[2];
      VTs[c4 * 4 + 3][r] = vv[3];
    }
#pragma unroll
    for (int it = 0; it < 5; ++it) {  // PQ/PK windows: 320 rows x 4 chunks
      int idx = t + it * 256;
      int r = idx >> 2, c4 = idx & 3;
      int p = wb + r; if (p > 510) p = 510;
      *(bf16x4*)&PQw[r][c4 * 4] = *(const bf16x4*)&PP[(size_t)p * 256 + e * 16 + c4 * 4];
      *(bf16x4*)&PKw[r][c4 * 4] = *(const bf16x4*)&PP[(size_t)p * 256 + 128 + e * 16 + c4 * 4];
    }
    __syncthreads();

    bf16x8 bQ = lo ? *(const bf16x8*)&Qs[16 * wv + ml][quad * 8] : zero8;
    f32x4 Ot = {0.f, 0.f, 0.f, 0.f};
    float den = 0.f;
#pragma unroll
    for (int jt = 0; jt < 16; ++jt) {
      const int j0 = jt * 16;
      bf16x8 aK = lo ? *(const bf16x8*)&Ks[j0 + ml][quad * 8] : zero8;
      const int pb = (PASS == 2) ? (16 * wv - j0 + 240) : (j0 - 16 * wv + 48);
      bf16x8 bPK0 = lo ? *(const bf16x8*)&PKw[pb + ml][quad * 8] : zero8;
      bf16x8 bPK1 = lo ? *(const bf16x8*)&PKw[pb + 16 + ml][quad * 8] : zero8;
      bf16x8 bPQ0 = lo ? *(const bf16x8*)&PQw[pb + ml][quad * 8] : zero8;
      bf16x8 bPQ1 = lo ? *(const bf16x8*)&PQw[pb + 16 + ml][quad * 8] : zero8;

      f32x4 St  = __builtin_amdgcn_mfma_f32_16x16x32_bf16(aK, bQ, z4, 0, 0, 0);
      f32x4 R2a = __builtin_amdgcn_mfma_f32_16x16x32_bf16(bQ, bPK0, z4, 0, 0, 0);
      f32x4 R2b = __builtin_amdgcn_mfma_f32_16x16x32_bf16(bQ, bPK1, z4, 0, 0, 0);
      f32x4 R3a = __builtin_amdgcn_mfma_f32_16x16x32_bf16(aK, bPQ0, z4, 0, 0, 0);
      f32x4 R3b = __builtin_amdgcn_mfma_f32_16x16x32_bf16(aK, bPQ1, z4, 0, 0, 0);
#pragma unroll
      for (int r = 0; r < 4; ++r) {
        R2s[wv][quad * 4 + r][ml]      = R2a[r];
        R2s[wv][quad * 4 + r][ml + 16] = R2b[r];
        R3s[wv][quad * 4 + r][ml]      = R3a[r];
        R3s[wv][quad * 4 + r][ml + 16] = R3b[r];
      }
#pragma unroll
      for (int r = 0; r < 4; ++r) {
        const int jl = quad * 4 + r;
        const int pcol = (PASS == 2) ? (ml - jl + 15) : (jl - ml + 15);
        float s = St[r] + R2s[wv][ml][pcol] + R3s[wv][jl][pcol];
        if (RAW) rawacc[(RAW ? (jt * 4 + r) : 0)] += s;
        float pe = __expf(s);
        den += pe;
        Ps[wv][ml][(jt & 1) * 16 + jl] = f2bf(pe);
      }
      if (jt & 1) {
        bf16x8 aVT = *(const bf16x8*)&VTs[ml][(jt >> 1) * 32 + quad * 8];
        bf16x8 bP  = *(const bf16x8*)&Ps[wv][ml][quad * 8];
        Ot = __builtin_amdgcn_mfma_f32_16x16x32_bf16(aVT, bP, Ot, 0, 0, 0);
      }
    }
    den += __shfl_xor(den, 16);
    den += __shfl_xor(den, 32);
    float inv = 1.f / den;
    bf16x4 ob;
    ob[0] = f2bf(Ot[0] * inv); ob[1] = f2bf(Ot[1] * inv);
    ob[2] = f2bf(Ot[2] * inv); ob[3] = f2bf(Ot[3] * inv);
    // Ot element (d = quad*4+r, i = ml): O[(i,n), e*16 + d]
    *(bf16x4*)&O[((size_t)(i0p + 16 * wv + ml) * NBd + n) * Cd + e * 16 + quad * 4] = ob;
  }

  if (RAW) {
    float* rr = &raw[(((size_t)(n & 1) * HNd + (n >> 1)) * Wd + (i0p + 16 * wv + ml)) * Wd];
#pragma unroll
    for (int jt = 0; jt < 16; ++jt) {
      float4 v;
      v.x = rawacc[RAW ? (jt * 4 + 0) : 0];
      v.y = rawacc[RAW ? (jt * 4 + 1) : 0];
      v.z = rawacc[RAW ? (jt * 4 + 2) : 0];
      v.w = rawacc[RAW ? (jt * 4 + 3) : 0];
      *(float4*)&rr[jt * 16 + quad * 4] = v;
    }
  }
}

extern "C" void kernel_launch(void* const* d_in, const int* in_sizes, int n_in,
                              void* d_out, int out_size, void* d_ws, size_t ws_size,
                              hipStream_t stream) {
  const float* feat_l = (const float*)d_in[0];
  const float* feat_r = (const float*)d_in[1];
  const float* pos    = (const float*)d_in[2];
  // d_in[3] = pos_indexes (int) -- structure known analytically, unused.
  const float* Wqkv = (const float*)d_in[4];
  const float* bqkv = (const float*)d_in[5];
  const float* Wo   = (const float*)d_in[6];
  const float* bo   = (const float*)d_in[7];
  const float* g1   = (const float*)d_in[8];
  const float* b1   = (const float*)d_in[9];
  const float* g2   = (const float*)d_in[10];
  const float* b2   = (const float*)d_in[11];
  float* out = (float*)d_out;

  float* ws = (float*)d_ws;
  float* fl_seq = ws;                 // fp32
  float* fr_seq = ws + SEQF;          // fp32
  float* fr2_f  = ws + 2 * SEQF;      // fp32 (fr_new)
  float* fl_new = ws + 3 * SEQF;      // fp32
  short* wsb    = (short*)(ws + 4 * SEQF);
  short* fl2_b   = wsb;               // SEQF bf16
  short* fr2_b   = wsb + SEQF;
  short* frb2_b  = wsb + 2 * SEQF;
  short* QKVl_b  = wsb + 3 * SEQF;    // 3*SEQF
  short* Qr_b    = wsb + 6 * SEQF;
  short* KVr2_b  = wsb + 7 * SEQF;    // 2*SEQF
  short* O_b     = wsb + 9 * SEQF;
  short* PP_b    = wsb + 10 * SEQF;   // 511*256
  short* Wb      = PP_b + 131072;     // Wqkv (49152) then Wo (16384)
  short* pos_b   = Wb + 65536;        // 511*128

  dim3 tgrid(8, 4, 128), tblk(32, 8);
  k_to_seq<<<tgrid, tblk, 0, stream>>>(feat_l, fl_seq);
  k_to_seq<<<tgrid, tblk, 0, stream>>>(feat_r, fr_seq);
  k_cvt<<<256, 256, 0, stream>>>(Wqkv, Wb, Wo, Wb + 49152, pos, pos_b);
  k_ln<<<32768, 128, 0, stream>>>(fl_seq, fl2_b, g1, b1);
  k_ln<<<32768, 128, 0, stream>>>(fr_seq, fr2_b, g1, b1);

  // PP = [PQ(scaled)|PK] projections of the 511 pos rows (bf16 out)
  k_gemm_bf<<<dim3(8, 2), 256, 0, stream>>>(pos_b, Wb, bqkv, nullptr, nullptr, PP_b,
                                            511, 256, 128, 0.25f);
  // QKV of fl2 (Q scaled)
  k_gemm_bf<<<dim3(512, 3), 256, 0, stream>>>(fl2_b, Wb, bqkv, nullptr, nullptr, QKVl_b,
                                              32768, 384, 128, 0.25f);
  // Q of fr2 (scaled)
  k_gemm_bf<<<dim3(512, 1), 256, 0, stream>>>(fr2_b, Wb, bqkv, nullptr, nullptr, Qr_b,
                                              32768, 128, 128, 0.25f);

  // mha1: q=fr2-proj, kv=fl2-proj, flipped pos => p = j-i+255
  k_attn_mfma<1, false><<<dim3(4, 128), 256, 0, stream>>>(
      Qr_b, Cd, QKVl_b + 128, QKVl_b + 256, 384, PP_b, O_b, nullptr);
  // fr_new = fr_seq + O @ Wo^T + bo (fp32 out)
  k_gemm_bf<<<dim3(512, 1), 256, 0, stream>>>(O_b, Wb + 49152, bo, fr_seq, fr2_f, nullptr,
                                              32768, 128, 0, 1.0f);
  // frb2 = ln(fr_new, g2, b2) (bf16)
  k_ln<<<32768, 128, 0, stream>>>(fr2_f, frb2_b, g2, b2);
  // KV of frb2
  k_gemm_bf<<<dim3(512, 2), 256, 0, stream>>>(frb2_b, Wb + 16384, bqkv + 128, nullptr,
                                              nullptr, KVr2_b, 32768, 256, 0, 1.0f);
  // mha2: q=fl2-proj (in QKVl), kv=frb2-proj; p = i-j+255; writes raw
  k_attn_mfma<2, true><<<dim3(4, 128), 256, 0, stream>>>(
      QKVl_b, 384, KVr2_b, KVr2_b + 128, 256, PP_b, O_b, out + 2 * SEQF);
  // fl_new = fl_seq + O @ Wo^T + bo
  k_gemm_bf<<<dim3(512, 1), 256, 0, stream>>>(O_b, Wb + 49152, bo, fl_seq, fl_new, nullptr,
                                              32768, 128, 0, 1.0f);

  k_from_seq<<<tgrid, tblk, 0, stream>>>(fl_new, out);
  k_from_seq<<<tgrid, tblk, 0, stream>>>(fr2_f, out + SEQF);

  (void)in_sizes; (void)n_in; (void)out_size; (void)ws_size;
}

// Round 5
// 473.419 us; speedup vs baseline: 2.3704x; 1.0517x over previous
//
#include <hip/hip_runtime.h>
#include <cstddef>

// Problem constants (fixed by setup_inputs)
static constexpr int Wd  = 256;   // sequence length (width)
static constexpr int NBd = 128;   // batch = hn*bs
static constexpr int Cd  = 128;   // channels
static constexpr int BSd = 2;     // bs
static constexpr int HNd = 64;    // hn
static constexpr size_t SEQF = (size_t)Wd * NBd * Cd;  // 4,194,304 elements

typedef __attribute__((ext_vector_type(8))) short bf16x8;
typedef __attribute__((ext_vector_type(4))) short bf16x4;
typedef __attribute__((ext_vector_type(2))) short bf16x2;
typedef __attribute__((ext_vector_type(4))) float f32x4;

__device__ inline short f2bf(float f) {
  union { float f; unsigned u; } v; v.f = f;
  return (short)((v.u + 0x7FFFu + ((v.u >> 16) & 1u)) >> 16);
}

// ---------------- to_seq: feat (bs,c,hn,w) -> seq (w, n=h*bs+b, c) fp32 ----------------
__global__ __launch_bounds__(256) void k_to_seq(const float* __restrict__ feat,
                                                float* __restrict__ out) {
  __shared__ float tile[32][33];
  int wi0 = blockIdx.x * 32, ci0 = blockIdx.y * 32;
  int hb = blockIdx.z;
  int h = hb >> 1, b = hb & 1;
  int tx = threadIdx.x, ty = threadIdx.y;
#pragma unroll
  for (int r = 0; r < 4; ++r) {
    int ci = ci0 + ty + r * 8;
    tile[ty + r * 8][tx] = feat[(((size_t)b * Cd + ci) * HNd + h) * Wd + wi0 + tx];
  }
  __syncthreads();
  int n = h * BSd + b;
#pragma unroll
  for (int r = 0; r < 4; ++r) {
    int wi = wi0 + ty + r * 8;
    out[((size_t)wi * NBd + n) * Cd + ci0 + tx] = tile[tx][ty + r * 8];
  }
}

// ---------------- from_seq: merged for both tensors ----------------
__global__ __launch_bounds__(256) void k_from_seq2(const float* __restrict__ seqA,
                                                   const float* __restrict__ seqB,
                                                   float* __restrict__ featA,
                                                   float* __restrict__ featB) {
  __shared__ float tile[32][33];
  int wi0 = blockIdx.x * 32, ci0 = blockIdx.y * 32;
  int z = blockIdx.z;
  const float* seq = (z < 128) ? seqA : seqB;
  float* feat = (z < 128) ? featA : featB;
  int hb = z & 127;
  int h = hb >> 1, b = hb & 1;
  int n = h * BSd + b;
  int tx = threadIdx.x, ty = threadIdx.y;
#pragma unroll
  for (int r = 0; r < 4; ++r) {
    int wi = wi0 + ty + r * 8;
    tile[ty + r * 8][tx] = seq[((size_t)wi * NBd + n) * Cd + ci0 + tx];
  }
  __syncthreads();
#pragma unroll
  for (int r = 0; r < 4; ++r) {
    int ci = ci0 + ty + r * 8;
    feat[(((size_t)b * Cd + ci) * HNd + h) * Wd + wi0 + tx] = tile[tx][ty + r * 8];
  }
}

// ---------------- LayerNorm: 8 rows per 512-thr block, wave per row ----------------
__global__ __launch_bounds__(512) void k_ln(const float* __restrict__ in,
                                            short* __restrict__ out,
                                            const float* __restrict__ g,
                                            const float* __restrict__ bb) {
  int wv = threadIdx.x >> 6, lane = threadIdx.x & 63;
  int row = blockIdx.x * 8 + wv;
  const float2 x2 = *(const float2*)&in[(size_t)row * Cd + lane * 2];
  float s1 = x2.x + x2.y, s2 = x2.x * x2.x + x2.y * x2.y;
#pragma unroll
  for (int m = 1; m < 64; m <<= 1) {
    s1 += __shfl_xor(s1, m);
    s2 += __shfl_xor(s2, m);
  }
  float mean = s1 * (1.0f / Cd);
  float var  = s2 * (1.0f / Cd) - mean * mean;
  float r = rsqrtf(var + 1e-5f);
  const float2 g2 = *(const float2*)&g[lane * 2];
  const float2 b2 = *(const float2*)&bb[lane * 2];
  bf16x2 o;
  o[0] = f2bf((x2.x - mean) * r * g2.x + b2.x);
  o[1] = f2bf((x2.y - mean) * r * g2.y + b2.y);
  *(bf16x2*)&out[(size_t)row * Cd + lane * 2] = o;
}

// ---------------- one-shot fp32->bf16 weight/pos convert ----------------
__global__ __launch_bounds__(256) void k_cvt(const float* __restrict__ w1, short* d1,  // 49152
                                             const float* __restrict__ w2, short* d2,  // 16384
                                             const float* __restrict__ w3, short* d3)  // 65408
{
  int i = blockIdx.x * 256 + threadIdx.x;
  if (i < 49152) d1[i] = f2bf(w1[i]);
  if (i < 16384) d2[i] = f2bf(w2[i]);
  if (i < 65408) d3[i] = f2bf(w3[i]);
}

// ---------------- bf16 MFMA GEMM, K=128, no LDS, no barriers ----------------
// out[m,n] = A[m]·Wt[n] + bias[n] (cols n<scaleN0 scaled), optional fp32 residual.
// Block 256 thr = 4 waves; block tile 64m x 128n; wave tile 64m x 32n.
// Merge: blocks with blockIdx.y >= yCut use A2/outB2/ldout2 (n-block from 0).
__global__ __launch_bounds__(256) void k_gemm_bf(
    const short* __restrict__ A, const short* __restrict__ Wt,
    const float* __restrict__ bias, const float* __restrict__ res,
    float* __restrict__ outF, short* __restrict__ outB,
    int M, int ldout, int scaleN0, float scale,
    const short* __restrict__ A2, short* __restrict__ outB2, int ldout2, int yCut) {
  const int t = threadIdx.x;
  const int lane = t & 63, wv = t >> 6;
  const int ml = lane & 15, quad = lane >> 4;
  const int m0 = blockIdx.x * 64;
  int yb = blockIdx.y;
  const short* Ap = A;
  short* oB = outB;
  float* oF = outF;
  const float* rs = res;
  int ld = ldout;
  int nblk = yb;
  if (yb >= yCut) { Ap = A2; oB = outB2; oF = nullptr; rs = nullptr; ld = ldout2; nblk = 0; }
  const int n0 = nblk * 128 + wv * 32;
  const bf16x8 zero8 = {0, 0, 0, 0, 0, 0, 0, 0};

  bf16x8 Bfr[2][4];
#pragma unroll
  for (int nf = 0; nf < 2; ++nf)
#pragma unroll
    for (int ks = 0; ks < 4; ++ks)
      Bfr[nf][ks] = *(const bf16x8*)&Wt[(size_t)(n0 + nf * 16 + ml) * 128 + ks * 32 + quad * 8];

  f32x4 acc[4][2];
#pragma unroll
  for (int mf = 0; mf < 4; ++mf)
#pragma unroll
    for (int nf = 0; nf < 2; ++nf) acc[mf][nf] = {0.f, 0.f, 0.f, 0.f};

#pragma unroll
  for (int ks = 0; ks < 4; ++ks) {
    bf16x8 Af[4];
#pragma unroll
    for (int mf = 0; mf < 4; ++mf) {
      int m = m0 + mf * 16 + ml;
      Af[mf] = (m < M) ? *(const bf16x8*)&Ap[(size_t)m * 128 + ks * 32 + quad * 8] : zero8;
    }
#pragma unroll
    for (int mf = 0; mf < 4; ++mf)
#pragma unroll
      for (int nf = 0; nf < 2; ++nf)
        acc[mf][nf] = __builtin_amdgcn_mfma_f32_16x16x32_bf16(Af[mf], Bfr[nf][ks], acc[mf][nf], 0, 0, 0);
  }

#pragma unroll
  for (int nf = 0; nf < 2; ++nf) {
    int n = n0 + nf * 16 + ml;
    float bi = bias[n];
    float sc = (n < scaleN0) ? scale : 1.0f;
#pragma unroll
    for (int mf = 0; mf < 4; ++mf) {
#pragma unroll
      for (int r = 0; r < 4; ++r) {
        int m = m0 + mf * 16 + quad * 4 + r;
        if (m >= M) continue;
        float v = (acc[mf][nf][r] + bi) * sc;
        if (rs) v += rs[(size_t)m * ld + n];
        if (oF) oF[(size_t)m * ld + n] = v;
        if (oB) oB[(size_t)m * ld + n] = f2bf(v);
      }
    }
  }
}

// ---------------- MFMA fused attention (bf16 in / bf16 out) ----------------
// LDS pads: rows read via bf16x8 (ds_read_b128) MUST be multiples of 8 shorts
// (16 B). Ks/Qs/PQw/PKw: 24 shorts (48 B) -> read bank groups at wave64 minimum.
// VTs: 272 shorts (544 B = 34*16) + row-linear stores (2-way = min).
// R2s 34 / R3s 35 (scalar f32, odd-ish pads). Ps 40 (80 B aligned).
// PASS==2: p = i-j+255. PASS==1: p = j-i+255. RAW (pass2): raw fp32 (bs,hn,w,w).
template <int PASS, bool RAW>
__global__ __launch_bounds__(256) void k_attn_mfma(
    const short* __restrict__ Qg, int ldq,
    const short* __restrict__ Kg, const short* __restrict__ Vg, int ldkv,
    const short* __restrict__ PP, short* __restrict__ O,
    float* __restrict__ raw) {
  __shared__ short Ks[256][24];
  __shared__ short Qs[64][24];
  __shared__ short VTs[16][272];
  __shared__ short PQw[320][24];
  __shared__ short PKw[320][24];
  __shared__ float R2s[4][16][34];
  __shared__ float R3s[4][16][35];
  __shared__ short Ps[4][16][40];

  const int t = threadIdx.x;
  const int n = blockIdx.y;
  const int i0p = blockIdx.x * 64;
  const int lane = t & 63, wv = t >> 6;
  const int ml = lane & 15, quad = lane >> 4;
  const bool lo = lane < 32;
  const int wb = (PASS == 2) ? i0p : (192 - i0p);
  const bf16x8 zero8 = {0, 0, 0, 0, 0, 0, 0, 0};
  const f32x4 z4 = {0.f, 0.f, 0.f, 0.f};

  float rawacc[RAW ? 64 : 1];
  if (RAW) {
#pragma unroll
    for (int z = 0; z < (RAW ? 64 : 1); ++z) rawacc[z] = 0.f;
  }

  for (int e = 0; e < 8; ++e) {
    __syncthreads();
    {  // stage Q panel: 64 rows x 4 bf16x4 chunks
      int r = t >> 2, c4 = t & 3;
      *(bf16x4*)&Qs[r][c4 * 4] =
          *(const bf16x4*)&Qg[((size_t)(i0p + r) * NBd + n) * ldq + e * 16 + c4 * 4];
    }
#pragma unroll
    for (int it = 0; it < 4; ++it) {  // K rows: 256 rows x 4 chunks
      int idx = t + it * 256;
      int r = idx >> 2, c4 = idx & 3;
      *(bf16x4*)&Ks[r][c4 * 4] =
          *(const bf16x4*)&Kg[((size_t)r * NBd + n) * ldkv + e * 16 + c4 * 4];
    }
#pragma unroll
    for (int it = 0; it < 4; ++it) {  // V transposed: row-linear lanes (2-way = min)
      bf16x4 vv = *(const bf16x4*)&Vg[((size_t)t * NBd + n) * ldkv + e * 16 + it * 4];
      VTs[it * 4 + 0][t] = vv[0];
      VTs[it * 4 + 1][t] = vv[1];
      VTs[it * 4 + 2][t] = vv[2];
      VTs[it * 4 + 3][t] = vv[3];
    }
#pragma unroll
    for (int it = 0; it < 5; ++it) {  // PQ/PK windows: 320 rows x 4 chunks
      int idx = t + it * 256;
      int r = idx >> 2, c4 = idx & 3;
      int p = wb + r; if (p > 510) p = 510;
      *(bf16x4*)&PQw[r][c4 * 4] = *(const bf16x4*)&PP[(size_t)p * 256 + e * 16 + c4 * 4];
      *(bf16x4*)&PKw[r][c4 * 4] = *(const bf16x4*)&PP[(size_t)p * 256 + 128 + e * 16 + c4 * 4];
    }
    __syncthreads();

    bf16x8 bQ = lo ? *(const bf16x8*)&Qs[16 * wv + ml][quad * 8] : zero8;
    f32x4 Ot = {0.f, 0.f, 0.f, 0.f};
    float den = 0.f;
#pragma unroll
    for (int jt = 0; jt < 16; ++jt) {
      const int j0 = jt * 16;
      bf16x8 aK = lo ? *(const bf16x8*)&Ks[j0 + ml][quad * 8] : zero8;
      const int pb = (PASS == 2) ? (16 * wv - j0 + 240) : (j0 - 16 * wv + 48);
      bf16x8 bPK0 = lo ? *(const bf16x8*)&PKw[pb + ml][quad * 8] : zero8;
      bf16x8 bPK1 = lo ? *(const bf16x8*)&PKw[pb + 16 + ml][quad * 8] : zero8;
      bf16x8 bPQ0 = lo ? *(const bf16x8*)&PQw[pb + ml][quad * 8] : zero8;
      bf16x8 bPQ1 = lo ? *(const bf16x8*)&PQw[pb + 16 + ml][quad * 8] : zero8;

      f32x4 St  = __builtin_amdgcn_mfma_f32_16x16x32_bf16(aK, bQ, z4, 0, 0, 0);
      f32x4 R2a = __builtin_amdgcn_mfma_f32_16x16x32_bf16(bQ, bPK0, z4, 0, 0, 0);
      f32x4 R2b = __builtin_amdgcn_mfma_f32_16x16x32_bf16(bQ, bPK1, z4, 0, 0, 0);
      f32x4 R3a = __builtin_amdgcn_mfma_f32_16x16x32_bf16(aK, bPQ0, z4, 0, 0, 0);
      f32x4 R3b = __builtin_amdgcn_mfma_f32_16x16x32_bf16(aK, bPQ1, z4, 0, 0, 0);
#pragma unroll
      for (int r = 0; r < 4; ++r) {
        R2s[wv][quad * 4 + r][ml]      = R2a[r];
        R2s[wv][quad * 4 + r][ml + 16] = R2b[r];
        R3s[wv][quad * 4 + r][ml]      = R3a[r];
        R3s[wv][quad * 4 + r][ml + 16] = R3b[r];
      }
#pragma unroll
      for (int r = 0; r < 4; ++r) {
        const int jl = quad * 4 + r;
        const int pcol = (PASS == 2) ? (ml - jl + 15) : (jl - ml + 15);
        float s = St[r] + R2s[wv][ml][pcol] + R3s[wv][jl][pcol];
        if (RAW) rawacc[(RAW ? (jt * 4 + r) : 0)] += s;
        float pe = __expf(s);
        den += pe;
        Ps[wv][ml][(jt & 1) * 16 + jl] = f2bf(pe);
      }
      if (jt & 1) {
        bf16x8 aVT = *(const bf16x8*)&VTs[ml][(jt >> 1) * 32 + quad * 8];
        bf16x8 bP  = *(const bf16x8*)&Ps[wv][ml][quad * 8];
        Ot = __builtin_amdgcn_mfma_f32_16x16x32_bf16(aVT, bP, Ot, 0, 0, 0);
      }
    }
    den += __shfl_xor(den, 16);
    den += __shfl_xor(den, 32);
    float inv = 1.f / den;
    bf16x4 ob;
    ob[0] = f2bf(Ot[0] * inv); ob[1] = f2bf(Ot[1] * inv);
    ob[2] = f2bf(Ot[2] * inv); ob[3] = f2bf(Ot[3] * inv);
    // Ot element (d = quad*4+r, i = ml): O[(i,n), e*16 + d]
    *(bf16x4*)&O[((size_t)(i0p + 16 * wv + ml) * NBd + n) * Cd + e * 16 + quad * 4] = ob;
  }

  if (RAW) {
    float* rr = &raw[(((size_t)(n & 1) * HNd + (n >> 1)) * Wd + (i0p + 16 * wv + ml)) * Wd];
#pragma unroll
    for (int jt = 0; jt < 16; ++jt) {
      float4 v;
      v.x = rawacc[RAW ? (jt * 4 + 0) : 0];
      v.y = rawacc[RAW ? (jt * 4 + 1) : 0];
      v.z = rawacc[RAW ? (jt * 4 + 2) : 0];
      v.w = rawacc[RAW ? (jt * 4 + 3) : 0];
      *(float4*)&rr[jt * 16 + quad * 4] = v;
    }
  }
}

extern "C" void kernel_launch(void* const* d_in, const int* in_sizes, int n_in,
                              void* d_out, int out_size, void* d_ws, size_t ws_size,
                              hipStream_t stream) {
  const float* feat_l = (const float*)d_in[0];
  const float* feat_r = (const float*)d_in[1];
  const float* pos    = (const float*)d_in[2];
  // d_in[3] = pos_indexes (int) -- structure known analytically, unused.
  const float* Wqkv = (const float*)d_in[4];
  const float* bqkv = (const float*)d_in[5];
  const float* Wo   = (const float*)d_in[6];
  const float* bo   = (const float*)d_in[7];
  const float* g1   = (const float*)d_in[8];
  const float* b1   = (const float*)d_in[9];
  const float* g2   = (const float*)d_in[10];
  const float* b2   = (const float*)d_in[11];
  float* out = (float*)d_out;

  float* ws = (float*)d_ws;
  float* fl_seq = ws;                 // fp32
  float* fr_seq = ws + SEQF;          // fp32
  float* fr2_f  = ws + 2 * SEQF;      // fp32 (fr_new)
  float* fl_new = ws + 3 * SEQF;      // fp32
  short* wsb    = (short*)(ws + 4 * SEQF);
  short* fl2_b   = wsb;               // SEQF bf16
  short* fr2_b   = wsb + SEQF;
  short* frb2_b  = wsb + 2 * SEQF;
  short* QKVl_b  = wsb + 3 * SEQF;    // 3*SEQF
  short* Qr_b    = wsb + 6 * SEQF;
  short* KVr2_b  = wsb + 7 * SEQF;    // 2*SEQF
  short* O_b     = wsb + 9 * SEQF;
  short* PP_b    = wsb + 10 * SEQF;   // 511*256
  short* Wb      = PP_b + 131072;     // Wqkv (49152) then Wo (16384)
  short* pos_b   = Wb + 65536;        // 511*128

  dim3 tgrid(8, 4, 128), tblk(32, 8);
  k_to_seq<<<tgrid, tblk, 0, stream>>>(feat_l, fl_seq);
  k_to_seq<<<tgrid, tblk, 0, stream>>>(feat_r, fr_seq);
  k_cvt<<<256, 256, 0, stream>>>(Wqkv, Wb, Wo, Wb + 49152, pos, pos_b);
  k_ln<<<4096, 512, 0, stream>>>(fl_seq, fl2_b, g1, b1);
  k_ln<<<4096, 512, 0, stream>>>(fr_seq, fr2_b, g1, b1);

  // PP = [PQ(scaled)|PK] projections of the 511 pos rows (bf16 out)
  k_gemm_bf<<<dim3(8, 2), 256, 0, stream>>>(pos_b, Wb, bqkv, nullptr, nullptr, PP_b,
                                            511, 256, 128, 0.25f,
                                            nullptr, nullptr, 0, 999);
  // QKV of fl2 (Q scaled) + Q of fr2 (scaled), merged
  k_gemm_bf<<<dim3(512, 4), 256, 0, stream>>>(fl2_b, Wb, bqkv, nullptr, nullptr, QKVl_b,
                                              32768, 384, 128, 0.25f,
                                              fr2_b, Qr_b, 128, 3);

  // mha1: q=fr2-proj, kv=fl2-proj, flipped pos => p = j-i+255
  k_attn_mfma<1, false><<<dim3(4, 128), 256, 0, stream>>>(
      Qr_b, Cd, QKVl_b + 128, QKVl_b + 256, 384, PP_b, O_b, nullptr);
  // fr_new = fr_seq + O @ Wo^T + bo (fp32 out)
  k_gemm_bf<<<dim3(512, 1), 256, 0, stream>>>(O_b, Wb + 49152, bo, fr_seq, fr2_f, nullptr,
                                              32768, 128, 0, 1.0f,
                                              nullptr, nullptr, 0, 999);
  // frb2 = ln(fr_new, g2, b2) (bf16)
  k_ln<<<4096, 512, 0, stream>>>(fr2_f, frb2_b, g2, b2);
  // KV of frb2
  k_gemm_bf<<<dim3(512, 2), 256, 0, stream>>>(frb2_b, Wb + 16384, bqkv + 128, nullptr,
                                              nullptr, KVr2_b, 32768, 256, 0, 1.0f,
                                              nullptr, nullptr, 0, 999);
  // mha2: q=fl2-proj (in QKVl), kv=frb2-proj; p = i-j+255; writes raw
  k_attn_mfma<2, true><<<dim3(4, 128), 256, 0, stream>>>(
      QKVl_b, 384, KVr2_b, KVr2_b + 128, 256, PP_b, O_b, out + 2 * SEQF);
  // fl_new = fl_seq + O @ Wo^T + bo
  k_gemm_bf<<<dim3(512, 1), 256, 0, stream>>>(O_b, Wb + 49152, bo, fl_seq, fl_new, nullptr,
                                              32768, 128, 0, 1.0f,
                                              nullptr, nullptr, 0, 999);

  k_from_seq2<<<dim3(8, 4, 256), tblk, 0, stream>>>(fl_new, fr2_f, out, out + SEQF);

  (void)in_sizes; (void)n_in; (void)out_size; (void)ws_size;
}